// Round 4
// baseline (69.944 us; speedup 1.0000x reference)
//
#include <hip/hip_runtime.h>

#define NG 2
#define NV 320
#define GV 640      // NG*NV
#define DHALF 128   // CODE_DIM/NG
#define BSROWS 2048 // B*S
#define NROWS 4096  // BSROWS*NG
#define K_DIM 512
#define NPART 256   // row-kernel blocks (partials)

typedef _Float16 half8 __attribute__((ext_vector_type(8)));
typedef _Float16 half4 __attribute__((ext_vector_type(4)));
typedef float floatx4 __attribute__((ext_vector_type(4)));

#define MFMA16(a, b, c) __builtin_amdgcn_mfma_f32_16x16x32_f16(a, b, c, 0, 0, 0)

// ---------------- Prep: W[512][640] f32 -> Wt_h/Wt_l [640][512] f16 (scale 1024); zero ctr --
__global__ __launch_bounds__(256) void prep_w_kernel(
    const float* __restrict__ W, _Float16* __restrict__ Wth, _Float16* __restrict__ Wtl,
    int* __restrict__ counter) {
  __shared__ float T[32][33];
  const int k0 = blockIdx.y * 32, n0 = blockIdx.x * 32;
  const int t = threadIdx.x;
  if (blockIdx.x == 0 && blockIdx.y == 0 && t == 0) *counter = 0;
  const int r = t >> 3, c4 = (t & 7) << 2;
  float4 v = *(const float4*)(W + (k0 + r) * GV + n0 + c4);
  T[r][c4 + 0] = v.x; T[r][c4 + 1] = v.y; T[r][c4 + 2] = v.z; T[r][c4 + 3] = v.w;
  __syncthreads();
  const int nr = t >> 3, k4 = (t & 7) << 2;
  half4 hv, lv;
#pragma unroll
  for (int j = 0; j < 4; ++j) {
    float s = T[k4 + j][nr] * 1024.0f;
    _Float16 h = (_Float16)s;
    hv[j] = h;
    lv[j] = (_Float16)(s - (float)h);
  }
  *(half4*)(Wth + (n0 + nr) * K_DIM + k0 + k4) = hv;
  *(half4*)(Wtl + (n0 + nr) * K_DIM + k0 + k4) = lv;
}

// ---------------- GEMM: logits = x @ W + b, barrier-free, global->reg fragments ------------
__global__ __launch_bounds__(256) void gemm_mfma_kernel(
    const float* __restrict__ X, const _Float16* __restrict__ Wth,
    const _Float16* __restrict__ Wtl, const float* __restrict__ bias,
    float* __restrict__ C) {
  const int tid = threadIdx.x;
  const int bm = blockIdx.y * 64, bn = blockIdx.x * 64;
  const int w = tid >> 6, lane = tid & 63;
  const int wr = w >> 1, wc = w & 1;
  const int frow = lane & 15;
  const int fkg = (lane >> 4) << 3;

  const float* Xa0 = X + (bm + wr * 32 + frow) * K_DIM + fkg;
  const float* Xa1 = Xa0 + 16 * K_DIM;
  const _Float16* Bh0g = Wth + (bn + wc * 32 + frow) * K_DIM + fkg;
  const _Float16* Bh1g = Bh0g + 16 * K_DIM;
  const _Float16* Bl0g = Wtl + (bn + wc * 32 + frow) * K_DIM + fkg;
  const _Float16* Bl1g = Bl0g + 16 * K_DIM;

  floatx4 acc[2][2] = {};

#pragma unroll
  for (int k0 = 0; k0 < K_DIM; k0 += 32) {
    float4 xa = *(const float4*)(Xa0 + k0);
    float4 xb = *(const float4*)(Xa0 + k0 + 4);
    float4 ya = *(const float4*)(Xa1 + k0);
    float4 yb = *(const float4*)(Xa1 + k0 + 4);
    half8 bh0 = *(const half8*)(Bh0g + k0);
    half8 bh1 = *(const half8*)(Bh1g + k0);
    half8 bl0 = *(const half8*)(Bl0g + k0);
    half8 bl1 = *(const half8*)(Bl1g + k0);

    float x0[8] = {xa.x, xa.y, xa.z, xa.w, xb.x, xb.y, xb.z, xb.w};
    float x1[8] = {ya.x, ya.y, ya.z, ya.w, yb.x, yb.y, yb.z, yb.w};
    half8 ah0, al0, ah1, al1;
#pragma unroll
    for (int j = 0; j < 8; ++j) {
      float s0 = x0[j] * 64.0f;
      _Float16 h0 = (_Float16)s0;
      ah0[j] = h0;
      al0[j] = (_Float16)(s0 - (float)h0);
      float s1 = x1[j] * 64.0f;
      _Float16 h1 = (_Float16)s1;
      ah1[j] = h1;
      al1[j] = (_Float16)(s1 - (float)h1);
    }

    acc[0][0] = MFMA16(ah0, bh0, acc[0][0]);
    acc[0][1] = MFMA16(ah0, bh1, acc[0][1]);
    acc[1][0] = MFMA16(ah1, bh0, acc[1][0]);
    acc[1][1] = MFMA16(ah1, bh1, acc[1][1]);
    acc[0][0] = MFMA16(ah0, bl0, acc[0][0]);
    acc[0][1] = MFMA16(ah0, bl1, acc[0][1]);
    acc[1][0] = MFMA16(ah1, bl0, acc[1][0]);
    acc[1][1] = MFMA16(ah1, bl1, acc[1][1]);
    acc[0][0] = MFMA16(al0, bh0, acc[0][0]);
    acc[0][1] = MFMA16(al0, bh1, acc[0][1]);
    acc[1][0] = MFMA16(al1, bh0, acc[1][0]);
    acc[1][1] = MFMA16(al1, bh1, acc[1][1]);
  }

  // C/D layout: col = lane&15, row = (lane>>4)*4 + reg
  const float inv = 1.0f / 65536.0f;
#pragma unroll
  for (int i = 0; i < 2; ++i)
#pragma unroll
    for (int j = 0; j < 2; ++j) {
      const int col = bn + wc * 32 + j * 16 + (lane & 15);
      const int r0 = bm + wr * 32 + i * 16 + ((lane >> 4) << 2);
      const float bb = bias[col];
#pragma unroll
      for (int q = 0; q < 4; ++q)
        C[(r0 + q) * GV + col] = acc[i][j][q] * inv + bb;
    }
}

// ---------------- Row kernel: 4 rows/wave (unrolled); fused gather; per-block partials -----
__global__ __launch_bounds__(256) void row_kernel(
    const float* __restrict__ logits, const float* __restrict__ gumbels,
    const float* __restrict__ cvs, float* __restrict__ out,
    float* __restrict__ part) {
  __shared__ float accW[4][2][NV];
  const int tid = threadIdx.x;
  const int lane = tid & 63;
  const int w = tid >> 6;
  const int rbase = blockIdx.x * 16 + w * 4;  // even

  float p0[5] = {}, p1[5] = {};

#pragma unroll
  for (int i = 0; i < 4; ++i) {
    const int r = rbase + i;
    const int bs = r >> 1, g = i & 1;  // g == r&1 since rbase is even
    const float* lrow = logits + bs * GV + g * NV;
    const float* grow = gumbels + r * NV;
    float lv[5], av[5];
#pragma unroll
    for (int j = 0; j < 5; ++j) {
      lv[j] = lrow[lane + 64 * j];
      av[j] = lv[j] + grow[lane + 64 * j];
    }
    // softmax of raw logits
    float m = lv[0];
#pragma unroll
    for (int j = 1; j < 5; ++j) m = fmaxf(m, lv[j]);
#pragma unroll
    for (int o = 32; o > 0; o >>= 1) m = fmaxf(m, __shfl_xor(m, o));
    float e[5];
    float s = 0.f;
#pragma unroll
    for (int j = 0; j < 5; ++j) {
      e[j] = expf(lv[j] - m);
      s += e[j];
    }
#pragma unroll
    for (int o = 32; o > 0; o >>= 1) s += __shfl_xor(s, o);
    const float inv = 1.f / s;
#pragma unroll
    for (int j = 0; j < 5; ++j) {
      if ((i & 1) == 0) p0[j] += e[j] * inv;
      else              p1[j] += e[j] * inv;
    }
    // argmax of l+gumbel (first-index tie-break)
    float bv = av[0];
    int bi = lane;
#pragma unroll
    for (int j = 1; j < 5; ++j) {
      if (av[j] > bv) { bv = av[j]; bi = lane + 64 * j; }
    }
#pragma unroll
    for (int o = 32; o > 0; o >>= 1) {
      float ov = __shfl_xor(bv, o);
      int oi = __shfl_xor(bi, o);
      if (ov > bv || (ov == bv && oi < bi)) { bv = ov; bi = oi; }
    }
    // fused gather
    const float2 cv = *(const float2*)(cvs + (g * NV + bi) * DHALF + lane * 2);
    *(float2*)(out + bs * 256 + g * DHALF + lane * 2) = cv;
  }

#pragma unroll
  for (int j = 0; j < 5; ++j) {
    accW[w][0][lane + 64 * j] = p0[j];
    accW[w][1][lane + 64 * j] = p1[j];
  }
  __syncthreads();
  for (int i = tid; i < GV; i += 256) {
    const int g = (i < NV) ? 0 : 1;
    const int c = (i < NV) ? i : i - NV;
    part[blockIdx.x * GV + i] =
        (accW[0][g][c] + accW[1][g][c]) + (accW[2][g][c] + accW[3][g][c]);
  }
}

// ---------------- Reduce partials + perplexity (last-block-done) ---------------------------
__global__ __launch_bounds__(256) void reduce_perp_kernel(
    const float* __restrict__ part, float* __restrict__ hpart,
    int* __restrict__ counter, float* __restrict__ perpOut) {
  const int t = threadIdx.x, lane = t & 63, w = t >> 6;
  const int col = blockIdx.x * 64 + lane;  // blocks 0..9; 0..4 group0, 5..9 group1
  float s = 0.f;
  for (int b = w; b < NPART; b += 4) s += part[b * GV + col];
  __shared__ float red[4][64];
  red[w][lane] = s;
  __syncthreads();
  if (w == 0) {
    const float cs = red[0][lane] + red[1][lane] + red[2][lane] + red[3][lane];
    const float mmean = cs * (1.0f / BSROWS);
    float h = mmean * logf(mmean + 1e-7f);
#pragma unroll
    for (int o = 32; o > 0; o >>= 1) h += __shfl_xor(h, o);
    if (lane == 0) {
      hpart[blockIdx.x] = h;
      __threadfence();
      const int old = atomicAdd(counter, 1);
      if (old == 9) {
        __threadfence();
        float h0 = 0.f, h1 = 0.f;
#pragma unroll
        for (int i = 0; i < 5; ++i) h0 += hpart[i];
#pragma unroll
        for (int i = 5; i < 10; ++i) h1 += hpart[i];
        perpOut[0] = expf(-h0) + expf(-h1);
      }
    }
  }
}

extern "C" void kernel_launch(void* const* d_in, const int* in_sizes, int n_in,
                              void* d_out, int out_size, void* d_ws, size_t ws_size,
                              hipStream_t stream) {
  const float* x = (const float*)d_in[0];
  const float* W = (const float*)d_in[1];
  const float* b = (const float*)d_in[2];
  const float* cvs = (const float*)d_in[3];
  const float* gum = (const float*)d_in[4];
  float* out = (float*)d_out;

  float* logits = (float*)d_ws;                     // 2048*640 f32
  float* part = logits + BSROWS * GV;               // 256*640 f32
  float* hpart = part + NPART * GV;                 // 16 f32
  int* counter = (int*)(hpart + 16);                // 1 i32 (+pad)
  _Float16* Wth = (_Float16*)(counter + 4);         // 640*512 f16
  _Float16* Wtl = Wth + GV * K_DIM;                 // 640*512 f16

  dim3 pgrid(GV / 32, K_DIM / 32);  // (20, 16)
  prep_w_kernel<<<pgrid, 256, 0, stream>>>(W, Wth, Wtl, counter);
  dim3 ggrid(GV / 64, BSROWS / 64);  // (10, 32)
  gemm_mfma_kernel<<<ggrid, 256, 0, stream>>>(x, Wth, Wtl, b, logits);
  row_kernel<<<NROWS / 16, 256, 0, stream>>>(logits, gum, cvs, out, part);
  reduce_perp_kernel<<<GV / 64, 256, 0, stream>>>(part, hpart, counter, out + BSROWS * 256);
}